// Round 15
// baseline (1499.685 us; speedup 1.0000x reference)
//
#include <hip/hip_runtime.h>

typedef _Float16 f16x8 __attribute__((ext_vector_type(8)));
typedef float    f32x4 __attribute__((ext_vector_type(4)));
typedef unsigned u32x4 __attribute__((ext_vector_type(4)));

#define DEV __device__ __forceinline__

DEV float fexp2(float x){ return __builtin_amdgcn_exp2f(x); }
DEV float frcp (float x){ return __builtin_amdgcn_rcpf(x); }

// Pre-scaled sigmoid: arg already multiplied by -log2e (folded into weights).
DEV float sgm(float p){ return frcp(1.0f + fexp2(p)); }
// tanh(c), natural-domain c.
DEV float tnc(float c){ return fmaf(2.f, sgm(c * -2.88539008177792682f), -1.f); }

DEV float shx(float v, int m){ return __shfl_xor(v, m, 64); }

// RNE f16 pack
DEV unsigned pkrne(float a, float b){
  unsigned short ha = __builtin_bit_cast(unsigned short, (_Float16)a);
  unsigned short hb = __builtin_bit_cast(unsigned short, (_Float16)b);
  return (unsigned)ha | ((unsigned)hb << 16);
}

#define L2E_N  (-1.44269504088896341f)
#define L2E2_N (-2.88539008177792682f)

// Producer/consumer wave pairs. Block = 256 thr = 4 waves on 4 SIMDs.
// Role pattern {P,C,P,C} flipped by (blockIdx>>8)&1 so co-resident blocks
// (b and b+256 share a CU under 8-XCD round-robin) pair every SIMD with 1P+1C.
// Producer (16 seqs/wave, R10 layout): LSTM1 + LSTM2, writes h2 packs to LDS.
// Consumer: LSTM3 + linear + output stores, lagging 1 step (double buffer),
// one __syncthreads per step. Shared A/B k-labeling k=4g+e, slots e<4 only.
__global__ __launch_bounds__(256, 2)
void lstm3_kernel(const float* __restrict__ x,
                  const float* __restrict__ w_ih1, const float* __restrict__ w_hh1,
                  const float* __restrict__ b_ih1, const float* __restrict__ b_hh1,
                  const float* __restrict__ w_ih2, const float* __restrict__ w_hh2,
                  const float* __restrict__ b_ih2, const float* __restrict__ b_hh2,
                  const float* __restrict__ w_ih3, const float* __restrict__ w_hh3,
                  const float* __restrict__ b_ih3, const float* __restrict__ b_hh3,
                  const float* __restrict__ w_lin, const float* __restrict__ b_lin,
                  float* __restrict__ out, int T)
{
  __shared__ unsigned long long lbuf[2][2][64];   // [pair][buf][lane]

  const int tid = threadIdx.x;
  const int l   = tid & 63;
  const int n   = l & 15;
  const int g   = l >> 4;
  const int wv  = tid >> 6;
  const int pr  = wv >> 1;                       // pair 0/1 within block
  const int par = (blockIdx.x >> 8) & 1;         // placement parity
  const bool isP = ((wv & 1) == par);
  const int seq = 16 * (blockIdx.x * 2 + pr) + n;

  // ---------------- LSTM1 (pre-scaled): rows g (i/f) and 4+g (g-gate/o) ----------------
  const int rA = g, rB = 4 + g;
  const float sAq = L2E_N;
  const float sBq = (g < 2) ? L2E2_N : L2E_N;
  const float m1  = (g < 2) ? 2.0f : 1.0f;
  const float a1  = (g < 2) ? -1.0f : 0.0f;
  const float w1ax = w_ih1[2*rA]*sAq,  w1ay = w_ih1[2*rA+1]*sAq;
  const float w1ah0 = w_hh1[2*rA]*sAq, w1ah1 = w_hh1[2*rA+1]*sAq;
  const float bbA  = (b_ih1[rA] + b_hh1[rA]) * sAq;
  const float w1bx = w_ih1[2*rB]*sBq,  w1by = w_ih1[2*rB+1]*sBq;
  const float w1bh0 = w_hh1[2*rB]*sBq, w1bh1 = w_hh1[2*rB+1]*sBq;
  const float bbB  = (b_ih1[rB] + b_hh1[rB]) * sBq;

  // ---------------- LSTM2: A fragments (pre-scaled) ----------------
  f16x8 af[4];   // w_hh2, slots e<4 = k 4g+e
  f16x8 a2f[4];  // w_ih2, g0 slots e0/e1
  f32x4 cb[4];
  #pragma unroll
  for (int t = 0; t < 4; ++t){
    const float sc = (t == 2) ? L2E2_N : L2E_N;
    #pragma unroll
    for (int e = 0; e < 8; ++e){
      float v = 0.0f;
      if (e < 4) v = w_hh2[(16*t + n)*16 + (4*g + e)];
      af[t][e] = (_Float16)(v * sc);
      float v2 = 0.0f;
      if (g == 0 && e < 2) v2 = w_ih2[(16*t + n)*2 + e];
      a2f[t][e] = (_Float16)(v2 * sc);
    }
    #pragma unroll
    for (int j = 0; j < 4; ++j){
      const int r = 16*t + 4*g + j;
      cb[t][j] = (b_ih2[r] + b_hh2[r]) * sc;
    }
  }

  // ---------------- LSTM3 lane-local (pre-scaled): A row n = gate (n&3) ----------------
  const float s3n = ((n & 3) == 2) ? L2E2_N : L2E_N;
  f16x8 a3f;
  #pragma unroll
  for (int e = 0; e < 8; ++e){
    float v = 0.0f;
    if (e < 4) v = w_ih3[16*(n & 3) + 4*g + e] * s3n;
    a3f[e] = (_Float16)v;
  }
  f32x4 c3v;
  c3v[0] = (b_ih3[0] + b_hh3[0]) * L2E_N;
  c3v[1] = (b_ih3[1] + b_hh3[1]) * L2E_N;
  c3v[2] = (b_ih3[2] + b_hh3[2]) * L2E2_N;
  c3v[3] = (b_ih3[3] + b_hh3[3]) * L2E_N;
  const float wh30 = w_hh3[0] * L2E_N,  wh31 = w_hh3[1] * L2E_N;
  const float wh32 = w_hh3[2] * L2E2_N, wh33 = w_hh3[3] * L2E_N;
  const float wl = w_lin[0], bl = b_lin[0];

  // ---------------- state ----------------
  float c1 = 0.f, c3 = 0.f;
  float c2[4] = {0.f, 0.f, 0.f, 0.f};
  float h1a_all = 0.f, h1b_all = 0.f, h3 = 0.f;
  unsigned h1p = 0u;

  const float* xrow = x + (size_t)seq * (size_t)(2*T);
  float*       orow = out + (size_t)seq * (size_t)T;

  float2 x_use = *(const float2*)(xrow);
  float2 x_pre = *(const float2*)(xrow + 2);

  #define LSTM1_STEP(X0, X1)                                                   \
  {                                                                            \
    const float gA = fmaf(w1ax, (X0), fmaf(w1ay, (X1),                         \
                     fmaf(w1ah0, h1a_all, fmaf(w1ah1, h1b_all, bbA))));        \
    const float gB = fmaf(w1bx, (X0), fmaf(w1by, (X1),                         \
                     fmaf(w1bh0, h1a_all, fmaf(w1bh1, h1b_all, bbB))));        \
    const float zA = sgm(gA);                                                  \
    const float zB = fmaf(sgm(gB), m1, a1);                                    \
    const float ig1 = zA * zB;                                                 \
    const float fm = shx(zA, 32);                                              \
    c1 = fmaf(fm, c1, ig1);                                                    \
    const float th1 = tnc(c1);                                                 \
    const float om = shx(zB, 32);                                              \
    const float h1v = om * th1;                                                \
    const float t16 = shx(h1v, 16);                                            \
    h1p = pkrne(h1v, t16);                                                     \
    const float a_c = (g & 1) ? t16 : h1v;                                     \
    const float b_c = (g & 1) ? h1v : t16;                                     \
    const float a32 = shx(a_c, 32);                                            \
    const float b32 = shx(b_c, 32);                                            \
    h1a_all = (g & 2) ? a32 : a_c;                                             \
    h1b_all = (g & 2) ? b32 : b_c;                                             \
  }

  LSTM1_STEP(x_use.x, x_use.y)        // h1(0)

  // prologue d_pre (h2_prev = 0)
  f32x4 dp0, dp1, dp2, dp3;
  {
    u32x4 bu; bu[0] = 0u; bu[1] = 0u; bu[2] = 0u; bu[3] = 0u;
    const f16x8 bv = __builtin_bit_cast(f16x8, bu);
    dp0 = __builtin_amdgcn_mfma_f32_16x16x32_f16(af[0], bv, cb[0], 0, 0, 0);
    dp1 = __builtin_amdgcn_mfma_f32_16x16x32_f16(af[1], bv, cb[1], 0, 0, 0);
    dp2 = __builtin_amdgcn_mfma_f32_16x16x32_f16(af[2], bv, cb[2], 0, 0, 0);
    dp3 = __builtin_amdgcn_mfma_f32_16x16x32_f16(af[3], bv, cb[3], 0, 0, 0);
  }

  float o0 = 0.f, o1 = 0.f, o2 = 0.f, o3 = 0.f;

  for (int t = 0; t <= T; ++t){
    if (isP && t < T){
      // ---------- inject h1(t) ----------
      u32x4 b2u; b2u[0] = (g == 0) ? h1p : 0u; b2u[1] = 0u; b2u[2] = 0u; b2u[3] = 0u;
      const f16x8 b2v = __builtin_bit_cast(f16x8, b2u);
      const f32x4 d0 = __builtin_amdgcn_mfma_f32_16x16x32_f16(a2f[0], b2v, dp0, 0, 0, 0);
      const f32x4 d1 = __builtin_amdgcn_mfma_f32_16x16x32_f16(a2f[1], b2v, dp1, 0, 0, 0);
      const f32x4 d2 = __builtin_amdgcn_mfma_f32_16x16x32_f16(a2f[2], b2v, dp2, 0, 0, 0);
      const f32x4 d3 = __builtin_amdgcn_mfma_f32_16x16x32_f16(a2f[3], b2v, dp3, 0, 0, 0);

      // ---------- x advance + prefetch ----------
      const float2 xv = x_pre;
      const int ti = t + 2;
      const int tc = (ti < T) ? ti : (T - 1);
      x_pre = *(const float2*)(xrow + 2*tc);

      // ---------- LSTM1 for step t+1 ----------
      LSTM1_STEP(xv.x, xv.y)

      // ---------- LSTM2 activations + cell ----------
      float h2l[4];
      #pragma unroll
      for (int j = 0; j < 4; ++j){
        const float ii = sgm(d0[j]);
        const float ff = sgm(d1[j]);
        const float gg = fmaf(2.f, sgm(d2[j]), -1.f);
        const float oo = sgm(d3[j]);
        c2[j] = fmaf(ff, c2[j], ii * gg);
        h2l[j] = oo * tnc(c2[j]);
      }
      const unsigned pAu = pkrne(h2l[0], h2l[1]);
      const unsigned pBu = pkrne(h2l[2], h2l[3]);

      // ---------- next d_pre ----------
      u32x4 bu; bu[0] = pAu; bu[1] = pBu; bu[2] = 0u; bu[3] = 0u;
      const f16x8 bv = __builtin_bit_cast(f16x8, bu);
      dp0 = __builtin_amdgcn_mfma_f32_16x16x32_f16(af[0], bv, cb[0], 0, 0, 0);
      dp1 = __builtin_amdgcn_mfma_f32_16x16x32_f16(af[1], bv, cb[1], 0, 0, 0);
      dp2 = __builtin_amdgcn_mfma_f32_16x16x32_f16(af[2], bv, cb[2], 0, 0, 0);
      dp3 = __builtin_amdgcn_mfma_f32_16x16x32_f16(af[3], bv, cb[3], 0, 0, 0);

      // ---------- publish h2 packs ----------
      lbuf[pr][t & 1][l] = ((unsigned long long)pBu << 32) | (unsigned long long)pAu;
    }

    if (!isP && t > 0){
      const int u = t - 1;
      const unsigned long long v = lbuf[pr][u & 1][l];
      const unsigned pAu = (unsigned)v;
      const unsigned pBu = (unsigned)(v >> 32);
      u32x4 bu; bu[0] = pAu; bu[1] = pBu; bu[2] = 0u; bu[3] = 0u;
      const f16x8 bv = __builtin_bit_cast(f16x8, bu);
      const f32x4 d3v = __builtin_amdgcn_mfma_f32_16x16x32_f16(a3f, bv, c3v, 0, 0, 0);
      const float p_i = fmaf(wh30, h3, d3v[0]);
      const float p_f = fmaf(wh31, h3, d3v[1]);
      const float p_g = fmaf(wh32, h3, d3v[2]);
      const float p_o = fmaf(wh33, h3, d3v[3]);
      const float i3 = sgm(p_i);
      const float f3 = sgm(p_f);
      const float g3 = fmaf(2.f, sgm(p_g), -1.f);
      const float q3 = sgm(p_o);
      c3 = fmaf(f3, c3, i3 * g3);
      h3 = q3 * tnc(c3);
      const float yv = fmaf(wl, h3, bl);

      const int ch = u >> 2;
      const int s  = u & 3;
      const bool cap = (g == (ch & 3));
      if      (s == 0) o0 = cap ? yv : o0;
      else if (s == 1) o1 = cap ? yv : o1;
      else if (s == 2) o2 = cap ? yv : o2;
      else             o3 = cap ? yv : o3;

      if ((u & 15) == 15){
        float4 o4; o4.x = o0; o4.y = o1; o4.z = o2; o4.w = o3;
        *(float4*)(orow + (u >> 4) * 16 + 4 * g) = o4;
      }
    }

    __syncthreads();
  }
  #undef LSTM1_STEP
}

extern "C" void kernel_launch(void* const* d_in, const int* in_sizes, int n_in,
                              void* d_out, int out_size, void* d_ws, size_t ws_size,
                              hipStream_t stream)
{
  const float* x     = (const float*)d_in[0];
  const float* w_ih1 = (const float*)d_in[1];
  const float* w_hh1 = (const float*)d_in[2];
  const float* b_ih1 = (const float*)d_in[3];
  const float* b_hh1 = (const float*)d_in[4];
  const float* w_ih2 = (const float*)d_in[5];
  const float* w_hh2 = (const float*)d_in[6];
  const float* b_ih2 = (const float*)d_in[7];
  const float* b_hh2 = (const float*)d_in[8];
  const float* w_ih3 = (const float*)d_in[9];
  const float* w_hh3 = (const float*)d_in[10];
  const float* b_ih3 = (const float*)d_in[11];
  const float* b_hh3 = (const float*)d_in[12];
  const float* w_lin = (const float*)d_in[13];
  const float* b_lin = (const float*)d_in[14];
  float* out = (float*)d_out;

  const int T = 2048;
  const int B = in_sizes[0] / (2 * T);     // 16384
  const int blocks = B / 32;               // 512: 2 producer + 2 consumer waves each

  lstm3_kernel<<<blocks, 256, 0, stream>>>(
      x, w_ih1, w_hh1, b_ih1, b_hh1,
      w_ih2, w_hh2, b_ih2, b_hh2,
      w_ih3, w_hh3, b_ih3, b_hh3,
      w_lin, b_lin, out, T);
}

// Round 16
// 1226.678 us; speedup vs baseline: 1.2226x; 1.2226x over previous
//
#include <hip/hip_runtime.h>

typedef _Float16 f16x8 __attribute__((ext_vector_type(8)));
typedef float    f32x4 __attribute__((ext_vector_type(4)));
typedef unsigned u32x4 __attribute__((ext_vector_type(4)));

#define DEV __device__ __forceinline__

DEV float fexp2(float x){ return __builtin_amdgcn_exp2f(x); }
DEV float frcp (float x){ return __builtin_amdgcn_rcpf(x); }

// Pre-scaled sigmoid: arg already multiplied by -log2e (folded into weights).
DEV float sgm(float p){ return frcp(1.0f + fexp2(p)); }
// tanh(c), natural-domain c.
DEV float tnc(float c){ return fmaf(2.f, sgm(c * -2.88539008177792682f), -1.f); }

DEV float shx(float v, int m){ return __shfl_xor(v, m, 64); }

// RNE f16 pack
DEV unsigned pkrne(float a, float b){
  unsigned short ha = __builtin_bit_cast(unsigned short, (_Float16)a);
  unsigned short hb = __builtin_bit_cast(unsigned short, (_Float16)b);
  return (unsigned)ha | ((unsigned)hb << 16);
}

#define L2E_N  (-1.44269504088896341f)
#define L2E2_N (-2.88539008177792682f)

// R14 base (16 seqs/wave, LSTM1 hoisted one step) with:
//  (1) h1 injection MERGED into the main MFMA via upper-half slots:
//      A slots e4/e5 on g0 = w_ih2 cols; B slots e4/e5 on g0 = h1a,h1b.
//      The MFMA contraction pairs A slot (g,e) with B slot (g,e); this
//      correspondence is validated for e<4 (R7-R10); this round tests e>=4
//      (R4-R6 failures were confounded by the permlane bug, fixed in R8).
//      9 -> 5 MFMAs/step, no d_pre chain.
//  (2) LSTM3 activations group-spread (R8's validated shuffle pattern):
//      group g evaluates gate g only; 10 -> 4 trans ops, bit-identical values.
// Lane l: n=l&15 (seq col / A-row), g=l>>4 (k-group).
__global__ __launch_bounds__(256, 1)
void lstm3_kernel(const float* __restrict__ x,
                  const float* __restrict__ w_ih1, const float* __restrict__ w_hh1,
                  const float* __restrict__ b_ih1, const float* __restrict__ b_hh1,
                  const float* __restrict__ w_ih2, const float* __restrict__ w_hh2,
                  const float* __restrict__ b_ih2, const float* __restrict__ b_hh2,
                  const float* __restrict__ w_ih3, const float* __restrict__ w_hh3,
                  const float* __restrict__ b_ih3, const float* __restrict__ b_hh3,
                  const float* __restrict__ w_lin, const float* __restrict__ b_lin,
                  float* __restrict__ out, int T)
{
  const int tid = threadIdx.x;
  const int l   = tid & 63;
  const int n   = l & 15;
  const int g   = l >> 4;
  const int wv  = tid >> 6;
  const int seq = 16 * (blockIdx.x * 4 + wv) + n;

  // ---------------- LSTM1 (pre-scaled): rows g (i/f) and 4+g (g-gate/o) ----------------
  const int rA = g, rB = 4 + g;
  const float sAq = L2E_N;
  const float sBq = (g < 2) ? L2E2_N : L2E_N;
  const float m1  = (g < 2) ? 2.0f : 1.0f;
  const float a1  = (g < 2) ? -1.0f : 0.0f;
  const float w1ax = w_ih1[2*rA]*sAq,  w1ay = w_ih1[2*rA+1]*sAq;
  const float w1ah0 = w_hh1[2*rA]*sAq, w1ah1 = w_hh1[2*rA+1]*sAq;
  const float bbA  = (b_ih1[rA] + b_hh1[rA]) * sAq;
  const float w1bx = w_ih1[2*rB]*sBq,  w1by = w_ih1[2*rB+1]*sBq;
  const float w1bh0 = w_hh1[2*rB]*sBq, w1bh1 = w_hh1[2*rB+1]*sBq;
  const float bbB  = (b_ih1[rB] + b_hh1[rB]) * sBq;

  // ---------------- LSTM2: merged A fragments (w_hh2 lower half + w_ih2 upper on g0) ----------------
  f16x8 af[4];
  f32x4 cb[4];
  #pragma unroll
  for (int t = 0; t < 4; ++t){
    const float sc = (t == 2) ? L2E2_N : L2E_N;
    #pragma unroll
    for (int e = 0; e < 8; ++e){
      float v = 0.0f;
      if (e < 4)                 v = w_hh2[(16*t + n)*16 + (4*g + e)];
      else if (g == 0 && e < 6)  v = w_ih2[(16*t + n)*2 + (e - 4)];
      af[t][e] = (_Float16)(v * sc);
    }
    #pragma unroll
    for (int j = 0; j < 4; ++j){
      const int r = 16*t + 4*g + j;
      cb[t][j] = (b_ih2[r] + b_hh2[r]) * sc;
    }
  }

  // ---------------- LSTM3 (pre-scaled): A row n = gate (n&3); spread acts ----------------
  const float s3n = ((n & 3) == 2) ? L2E2_N : L2E_N;
  f16x8 a3f;
  #pragma unroll
  for (int e = 0; e < 8; ++e){
    float v = 0.0f;
    if (e < 4) v = w_ih3[16*(n & 3) + 4*g + e] * s3n;
    a3f[e] = (_Float16)v;
  }
  f32x4 c3v;
  c3v[0] = (b_ih3[0] + b_hh3[0]) * L2E_N;
  c3v[1] = (b_ih3[1] + b_hh3[1]) * L2E_N;
  c3v[2] = (b_ih3[2] + b_hh3[2]) * L2E2_N;
  c3v[3] = (b_ih3[3] + b_hh3[3]) * L2E_N;
  // group g owns gate g:
  const float s3g  = (g == 2) ? L2E2_N : L2E_N;
  const float m3g  = (g == 2) ? 2.0f : 1.0f;
  const float a3g  = (g == 2) ? -1.0f : 0.0f;
  const float wh3own = w_hh3[g] * s3g;
  const float wl = w_lin[0], bl = b_lin[0];

  // ---------------- state ----------------
  float c1 = 0.f, c3 = 0.f;
  float c2[4] = {0.f, 0.f, 0.f, 0.f};
  float h1a_all = 0.f, h1b_all = 0.f, h3_all = 0.f;
  unsigned pAu = 0u, pBu = 0u;
  unsigned h1p = 0u;

  const float* xrow = x + (size_t)seq * (size_t)(2*T);
  float*       orow = out + (size_t)seq * (size_t)T;

  float2 x_use = *(const float2*)(xrow);
  float2 x_pre = *(const float2*)(xrow + 2);

  #define LSTM1_STEP(X0, X1)                                                   \
  {                                                                            \
    const float gA = fmaf(w1ax, (X0), fmaf(w1ay, (X1),                         \
                     fmaf(w1ah0, h1a_all, fmaf(w1ah1, h1b_all, bbA))));        \
    const float gB = fmaf(w1bx, (X0), fmaf(w1by, (X1),                         \
                     fmaf(w1bh0, h1a_all, fmaf(w1bh1, h1b_all, bbB))));        \
    const float zA = sgm(gA);                                                  \
    const float zB = fmaf(sgm(gB), m1, a1);                                    \
    const float ig1 = zA * zB;                                                 \
    const float fm = shx(zA, 32);                                              \
    c1 = fmaf(fm, c1, ig1);                                                    \
    const float th1 = tnc(c1);                                                 \
    const float om = shx(zB, 32);                                              \
    const float h1v = om * th1;                                                \
    const float t16 = shx(h1v, 16);                                            \
    h1p = pkrne(h1v, t16);   /* meaningful on g0 lanes */                      \
    const float a_c = (g & 1) ? t16 : h1v;                                     \
    const float b_c = (g & 1) ? h1v : t16;                                     \
    const float a32 = shx(a_c, 32);                                            \
    const float b32 = shx(b_c, 32);                                            \
    h1a_all = (g & 2) ? a32 : a_c;                                             \
    h1b_all = (g & 2) ? b32 : b_c;                                             \
  }

  LSTM1_STEP(x_use.x, x_use.y)        // h1(0) -> h1p

  float o0 = 0.f, o1 = 0.f, o2 = 0.f, o3 = 0.f;

  const int NCH = T / 4;
  for (int ch = 0; ch < NCH; ++ch){
    const bool cap = (g == (ch & 3));

    #pragma unroll
    for (int s = 0; s < 4; ++s){
      // ---------- main MFMA: gates = W_hh2*h2(t-1) + W_ih2*h1(t) + bias ----------
      u32x4 bu; bu[0] = pAu; bu[1] = pBu; bu[2] = (g == 0) ? h1p : 0u; bu[3] = 0u;
      const f16x8 bv = __builtin_bit_cast(f16x8, bu);
      const f32x4 d0 = __builtin_amdgcn_mfma_f32_16x16x32_f16(af[0], bv, cb[0], 0, 0, 0);
      const f32x4 d1 = __builtin_amdgcn_mfma_f32_16x16x32_f16(af[1], bv, cb[1], 0, 0, 0);
      const f32x4 d2 = __builtin_amdgcn_mfma_f32_16x16x32_f16(af[2], bv, cb[2], 0, 0, 0);
      const f32x4 d3 = __builtin_amdgcn_mfma_f32_16x16x32_f16(af[3], bv, cb[3], 0, 0, 0);

      // ---------- x advance + prefetch (fills MFMA shadow) ----------
      const float2 xv = x_pre;
      const int ti = 4*ch + s + 2;
      const int tc = (ti < T) ? ti : (T - 1);
      x_pre = *(const float2*)(xrow + 2*tc);

      // ---------- LSTM1 for step t+1 (independent; interleaves with MFMA) ----------
      LSTM1_STEP(xv.x, xv.y)

      // ---------- LSTM2 activations + cell ----------
      float h2l[4];
      #pragma unroll
      for (int j = 0; j < 4; ++j){
        const float ii = sgm(d0[j]);
        const float ff = sgm(d1[j]);
        const float gg = fmaf(2.f, sgm(d2[j]), -1.f);
        const float oo = sgm(d3[j]);
        c2[j] = fmaf(ff, c2[j], ii * gg);
        h2l[j] = oo * tnc(c2[j]);
      }
      pAu = pkrne(h2l[0], h2l[1]);
      pBu = pkrne(h2l[2], h2l[3]);

      // ---------- LSTM3 MFMA (B upper slots zero) ----------
      u32x4 b3; b3[0] = pAu; b3[1] = pBu; b3[2] = 0u; b3[3] = 0u;
      const f16x8 b3v = __builtin_bit_cast(f16x8, b3);
      const f32x4 d3v = __builtin_amdgcn_mfma_f32_16x16x32_f16(a3f, b3v, c3v, 0, 0, 0);

      // ---------- LSTM3 acts: group g evaluates gate g (R8 pattern) ----------
      const float pg = (g == 0) ? d3v[0] : (g == 1) ? d3v[1] : (g == 2) ? d3v[2] : d3v[3];
      const float P  = fmaf(wh3own, h3_all, pg);
      const float z  = fmaf(sgm(P), m3g, a3g);      // g0:i g1:f g2:g g3:o
      const float gv = shx(z, 32);                  // g0<-g-val, g1<-o
      const float ig3 = z * gv;                     // g0: i*g
      const float fv = shx(z, 16);                  // g0<-f
      c3 = fmaf(fv, c3, ig3);                       // valid g0
      const float th3 = tnc(c3);
      const float ov3 = shx(gv, 16);                // g0<-o
      const float h3v = ov3 * th3;                  // valid g0
      const float u16 = shx(h3v, 16);
      const float selh = (g & 1) ? u16 : h3v;
      const float u32v = shx(selh, 32);
      h3_all = (g & 2) ? u32v : selh;
      const float yv = fmaf(wl, h3_all, bl);

      if      (s == 0) o0 = cap ? yv : o0;
      else if (s == 1) o1 = cap ? yv : o1;
      else if (s == 2) o2 = cap ? yv : o2;
      else             o3 = cap ? yv : o3;
    }

    if ((ch & 3) == 3){
      float4 o4; o4.x = o0; o4.y = o1; o4.z = o2; o4.w = o3;
      *(float4*)(orow + (ch >> 2) * 16 + 4 * g) = o4;
    }
  }
  #undef LSTM1_STEP
}

extern "C" void kernel_launch(void* const* d_in, const int* in_sizes, int n_in,
                              void* d_out, int out_size, void* d_ws, size_t ws_size,
                              hipStream_t stream)
{
  const float* x     = (const float*)d_in[0];
  const float* w_ih1 = (const float*)d_in[1];
  const float* w_hh1 = (const float*)d_in[2];
  const float* b_ih1 = (const float*)d_in[3];
  const float* b_hh1 = (const float*)d_in[4];
  const float* w_ih2 = (const float*)d_in[5];
  const float* w_hh2 = (const float*)d_in[6];
  const float* b_ih2 = (const float*)d_in[7];
  const float* b_hh2 = (const float*)d_in[8];
  const float* w_ih3 = (const float*)d_in[9];
  const float* w_hh3 = (const float*)d_in[10];
  const float* b_ih3 = (const float*)d_in[11];
  const float* b_hh3 = (const float*)d_in[12];
  const float* w_lin = (const float*)d_in[13];
  const float* b_lin = (const float*)d_in[14];
  float* out = (float*)d_out;

  const int T = 2048;
  const int B = in_sizes[0] / (2 * T);     // 16384
  const int waves   = B / 16;              // 1024
  const int blocks  = waves / 4;           // 256

  lstm3_kernel<<<blocks, 256, 0, stream>>>(
      x, w_ih1, w_hh1, b_ih1, b_hh1,
      w_ih2, w_hh2, b_ih2, b_hh2,
      w_ih3, w_hh3, b_ih3, b_hh3,
      w_lin, b_lin, out, T);
}

// Round 17
// 1064.888 us; speedup vs baseline: 1.4083x; 1.1519x over previous
//
#include <hip/hip_runtime.h>

typedef _Float16 f16x8 __attribute__((ext_vector_type(8)));
typedef float    f32x4 __attribute__((ext_vector_type(4)));
typedef unsigned u32x4 __attribute__((ext_vector_type(4)));

#define DEV __device__ __forceinline__

DEV float fexp2(float x){ return __builtin_amdgcn_exp2f(x); }
DEV float frcp (float x){ return __builtin_amdgcn_rcpf(x); }

// Pre-scaled sigmoid: arg already multiplied by -log2e (folded into weights).
DEV float sgm(float p){ return frcp(1.0f + fexp2(p)); }
// tanh(c), natural-domain c.
DEV float tnc(float c){ return fmaf(2.f, sgm(c * -2.88539008177792682f), -1.f); }

DEV float shx(float v, int m){ return __shfl_xor(v, m, 64); }

// RNE f16 pack
DEV unsigned pkrne(float a, float b){
  unsigned short ha = __builtin_bit_cast(unsigned short, (_Float16)a);
  unsigned short hb = __builtin_bit_cast(unsigned short, (_Float16)b);
  return (unsigned)ha | ((unsigned)hb << 16);
}

#define L2E_N  (-1.44269504088896341f)
#define L2E2_N (-2.88539008177792682f)

// R14 structure (16 seqs/wave, LSTM1 hoisted one step, lane-local LSTM3 --
// shuffle-free recurrence chains; R16 showed DS-shuffle latency on the h3
// chain costs ~175cy/step at 1 wave/SIMD) + R16's VALIDATED merged MFMA:
// h1 injection in upper k-slots (A e4/e5 on g0 = w_ih2; B word2 = h1p on all
// lanes -- A is zero there for g!=0 so no masking needed). 5 MFMAs/step.
// Lane l: n=l&15 (seq col / A-row), g=l>>4 (k-group).
__global__ __launch_bounds__(256, 1)
void lstm3_kernel(const float* __restrict__ x,
                  const float* __restrict__ w_ih1, const float* __restrict__ w_hh1,
                  const float* __restrict__ b_ih1, const float* __restrict__ b_hh1,
                  const float* __restrict__ w_ih2, const float* __restrict__ w_hh2,
                  const float* __restrict__ b_ih2, const float* __restrict__ b_hh2,
                  const float* __restrict__ w_ih3, const float* __restrict__ w_hh3,
                  const float* __restrict__ b_ih3, const float* __restrict__ b_hh3,
                  const float* __restrict__ w_lin, const float* __restrict__ b_lin,
                  float* __restrict__ out, int T)
{
  const int tid = threadIdx.x;
  const int l   = tid & 63;
  const int n   = l & 15;
  const int g   = l >> 4;
  const int wv  = tid >> 6;
  const int seq = 16 * (blockIdx.x * 4 + wv) + n;

  // ---------------- LSTM1 (pre-scaled): rows g (i/f) and 4+g (g-gate/o) ----------------
  const int rA = g, rB = 4 + g;
  const float sAq = L2E_N;
  const float sBq = (g < 2) ? L2E2_N : L2E_N;
  const float m1  = (g < 2) ? 2.0f : 1.0f;
  const float a1  = (g < 2) ? -1.0f : 0.0f;
  const float w1ax = w_ih1[2*rA]*sAq,  w1ay = w_ih1[2*rA+1]*sAq;
  const float w1ah0 = w_hh1[2*rA]*sAq, w1ah1 = w_hh1[2*rA+1]*sAq;
  const float bbA  = (b_ih1[rA] + b_hh1[rA]) * sAq;
  const float w1bx = w_ih1[2*rB]*sBq,  w1by = w_ih1[2*rB+1]*sBq;
  const float w1bh0 = w_hh1[2*rB]*sBq, w1bh1 = w_hh1[2*rB+1]*sBq;
  const float bbB  = (b_ih1[rB] + b_hh1[rB]) * sBq;

  // ---------------- LSTM2: merged A fragments (w_hh2 lower + w_ih2 upper on g0) ----------------
  f16x8 af[4];
  f32x4 cb[4];
  #pragma unroll
  for (int t = 0; t < 4; ++t){
    const float sc = (t == 2) ? L2E2_N : L2E_N;
    #pragma unroll
    for (int e = 0; e < 8; ++e){
      float v = 0.0f;
      if (e < 4)                 v = w_hh2[(16*t + n)*16 + (4*g + e)];
      else if (g == 0 && e < 6)  v = w_ih2[(16*t + n)*2 + (e - 4)];
      af[t][e] = (_Float16)(v * sc);
    }
    #pragma unroll
    for (int j = 0; j < 4; ++j){
      const int r = 16*t + 4*g + j;
      cb[t][j] = (b_ih2[r] + b_hh2[r]) * sc;
    }
  }

  // ---------------- LSTM3 lane-local (pre-scaled): A row n = gate (n&3) ----------------
  const float s3n = ((n & 3) == 2) ? L2E2_N : L2E_N;
  f16x8 a3f;
  #pragma unroll
  for (int e = 0; e < 8; ++e){
    float v = 0.0f;
    if (e < 4) v = w_ih3[16*(n & 3) + 4*g + e] * s3n;
    a3f[e] = (_Float16)v;
  }
  f32x4 c3v;
  c3v[0] = (b_ih3[0] + b_hh3[0]) * L2E_N;
  c3v[1] = (b_ih3[1] + b_hh3[1]) * L2E_N;
  c3v[2] = (b_ih3[2] + b_hh3[2]) * L2E2_N;
  c3v[3] = (b_ih3[3] + b_hh3[3]) * L2E_N;
  const float wh30 = w_hh3[0] * L2E_N,  wh31 = w_hh3[1] * L2E_N;
  const float wh32 = w_hh3[2] * L2E2_N, wh33 = w_hh3[3] * L2E_N;
  const float wl = w_lin[0], bl = b_lin[0];

  // ---------------- state ----------------
  float c1 = 0.f, c3 = 0.f;
  float c2[4] = {0.f, 0.f, 0.f, 0.f};
  float h1a_all = 0.f, h1b_all = 0.f, h3 = 0.f;
  unsigned pAu = 0u, pBu = 0u;
  unsigned h1p = 0u;

  const float* xrow = x + (size_t)seq * (size_t)(2*T);
  float*       orow = out + (size_t)seq * (size_t)T;

  float2 x_use = *(const float2*)(xrow);
  float2 x_pre = *(const float2*)(xrow + 2);

  #define LSTM1_STEP(X0, X1)                                                   \
  {                                                                            \
    const float gA = fmaf(w1ax, (X0), fmaf(w1ay, (X1),                         \
                     fmaf(w1ah0, h1a_all, fmaf(w1ah1, h1b_all, bbA))));        \
    const float gB = fmaf(w1bx, (X0), fmaf(w1by, (X1),                         \
                     fmaf(w1bh0, h1a_all, fmaf(w1bh1, h1b_all, bbB))));        \
    const float zA = sgm(gA);                                                  \
    const float zB = fmaf(sgm(gB), m1, a1);                                    \
    const float ig1 = zA * zB;                                                 \
    const float fm = shx(zA, 32);                                              \
    c1 = fmaf(fm, c1, ig1);                                                    \
    const float th1 = tnc(c1);                                                 \
    const float om = shx(zB, 32);                                              \
    const float h1v = om * th1;                                                \
    const float t16 = shx(h1v, 16);                                            \
    h1p = pkrne(h1v, t16);   /* meaningful on g0 lanes */                      \
    const float a_c = (g & 1) ? t16 : h1v;                                     \
    const float b_c = (g & 1) ? h1v : t16;                                     \
    const float a32 = shx(a_c, 32);                                            \
    const float b32 = shx(b_c, 32);                                            \
    h1a_all = (g & 2) ? a32 : a_c;                                             \
    h1b_all = (g & 2) ? b32 : b_c;                                             \
  }

  LSTM1_STEP(x_use.x, x_use.y)        // h1(0) -> h1p

  float o0 = 0.f, o1 = 0.f, o2 = 0.f, o3 = 0.f;

  const int NCH = T / 4;
  for (int ch = 0; ch < NCH; ++ch){
    const bool cap = (g == (ch & 3));

    #pragma unroll
    for (int s = 0; s < 4; ++s){
      // ---------- main MFMA: gates = W_hh2*h2(t-1) + W_ih2*h1(t) + bias ----------
      u32x4 bu; bu[0] = pAu; bu[1] = pBu; bu[2] = h1p; bu[3] = 0u;
      const f16x8 bv = __builtin_bit_cast(f16x8, bu);
      const f32x4 d0 = __builtin_amdgcn_mfma_f32_16x16x32_f16(af[0], bv, cb[0], 0, 0, 0);
      const f32x4 d1 = __builtin_amdgcn_mfma_f32_16x16x32_f16(af[1], bv, cb[1], 0, 0, 0);
      const f32x4 d2 = __builtin_amdgcn_mfma_f32_16x16x32_f16(af[2], bv, cb[2], 0, 0, 0);
      const f32x4 d3 = __builtin_amdgcn_mfma_f32_16x16x32_f16(af[3], bv, cb[3], 0, 0, 0);

      // ---------- x advance + prefetch (fills MFMA shadow) ----------
      const float2 xv = x_pre;
      const int ti = 4*ch + s + 2;
      const int tc = (ti < T) ? ti : (T - 1);
      x_pre = *(const float2*)(xrow + 2*tc);

      // ---------- LSTM1 for step t+1 (independent; interleaves with MFMA) ----------
      LSTM1_STEP(xv.x, xv.y)

      // ---------- LSTM2 activations + cell ----------
      float h2l[4];
      #pragma unroll
      for (int j = 0; j < 4; ++j){
        const float ii = sgm(d0[j]);
        const float ff = sgm(d1[j]);
        const float gg = fmaf(2.f, sgm(d2[j]), -1.f);
        const float oo = sgm(d3[j]);
        c2[j] = fmaf(ff, c2[j], ii * gg);
        h2l[j] = oo * tnc(c2[j]);
      }
      pAu = pkrne(h2l[0], h2l[1]);
      pBu = pkrne(h2l[2], h2l[3]);

      // ---------- LSTM3: lane-local (all 4 gates in d3v; no shuffles) ----------
      u32x4 b3; b3[0] = pAu; b3[1] = pBu; b3[2] = 0u; b3[3] = 0u;
      const f16x8 b3v = __builtin_bit_cast(f16x8, b3);
      const f32x4 d3v = __builtin_amdgcn_mfma_f32_16x16x32_f16(a3f, b3v, c3v, 0, 0, 0);
      const float p_i = fmaf(wh30, h3, d3v[0]);
      const float p_f = fmaf(wh31, h3, d3v[1]);
      const float p_g = fmaf(wh32, h3, d3v[2]);
      const float p_o = fmaf(wh33, h3, d3v[3]);
      const float i3 = sgm(p_i);
      const float f3 = sgm(p_f);
      const float g3 = fmaf(2.f, sgm(p_g), -1.f);
      const float q3 = sgm(p_o);
      c3 = fmaf(f3, c3, i3 * g3);
      h3 = q3 * tnc(c3);
      const float yv = fmaf(wl, h3, bl);

      if      (s == 0) o0 = cap ? yv : o0;
      else if (s == 1) o1 = cap ? yv : o1;
      else if (s == 2) o2 = cap ? yv : o2;
      else             o3 = cap ? yv : o3;
    }

    if ((ch & 3) == 3){
      float4 o4; o4.x = o0; o4.y = o1; o4.z = o2; o4.w = o3;
      *(float4*)(orow + (ch >> 2) * 16 + 4 * g) = o4;
    }
  }
  #undef LSTM1_STEP
}

extern "C" void kernel_launch(void* const* d_in, const int* in_sizes, int n_in,
                              void* d_out, int out_size, void* d_ws, size_t ws_size,
                              hipStream_t stream)
{
  const float* x     = (const float*)d_in[0];
  const float* w_ih1 = (const float*)d_in[1];
  const float* w_hh1 = (const float*)d_in[2];
  const float* b_ih1 = (const float*)d_in[3];
  const float* b_hh1 = (const float*)d_in[4];
  const float* w_ih2 = (const float*)d_in[5];
  const float* w_hh2 = (const float*)d_in[6];
  const float* b_ih2 = (const float*)d_in[7];
  const float* b_hh2 = (const float*)d_in[8];
  const float* w_ih3 = (const float*)d_in[9];
  const float* w_hh3 = (const float*)d_in[10];
  const float* b_ih3 = (const float*)d_in[11];
  const float* b_hh3 = (const float*)d_in[12];
  const float* w_lin = (const float*)d_in[13];
  const float* b_lin = (const float*)d_in[14];
  float* out = (float*)d_out;

  const int T = 2048;
  const int B = in_sizes[0] / (2 * T);     // 16384
  const int waves   = B / 16;              // 1024
  const int blocks  = waves / 4;           // 256

  lstm3_kernel<<<blocks, 256, 0, stream>>>(
      x, w_ih1, w_hh1, b_ih1, b_hh1,
      w_ih2, w_hh2, b_ih2, b_hh2,
      w_ih3, w_hh3, b_ih3, b_hh3,
      w_lin, b_lin, out, T);
}

// Round 18
// 1047.566 us; speedup vs baseline: 1.4316x; 1.0165x over previous
//
#include <hip/hip_runtime.h>

typedef _Float16 f16x8 __attribute__((ext_vector_type(8)));
typedef float    f32x4 __attribute__((ext_vector_type(4)));
typedef unsigned u32x4 __attribute__((ext_vector_type(4)));

#define DEV __device__ __forceinline__

DEV float fexp2(float x){ return __builtin_amdgcn_exp2f(x); }
DEV float frcp (float x){ return __builtin_amdgcn_rcpf(x); }

// Pre-scaled sigmoid: arg already multiplied by -log2e (folded into weights).
DEV float sgm(float p){ return frcp(1.0f + fexp2(p)); }
// tanh(c), natural-domain c.
DEV float tnc(float c){ return fmaf(2.f, sgm(c * -2.88539008177792682f), -1.f); }

DEV float shx(float v, int m){ return __shfl_xor(v, m, 64); }

// RTZ packed f16 (1 op). Safe: R4/R5 showed pack rounding doesn't move the
// recurrence, and absmax sits at 1 bf16 ulp with 4x threshold headroom.
DEV unsigned pkrtz(float a, float b){
  auto h = __builtin_amdgcn_cvt_pkrtz(a, b);
  return __builtin_bit_cast(unsigned, h);
}

#define L2E_N  (-1.44269504088896341f)
#define L2E2_N (-2.88539008177792682f)

// R17 structure (16 seqs/wave, merged h1-injection in upper k-slots, lane-local
// LSTM3, LSTM1 hoisted one step) + single shared B operand: LSTM3(t) and main
// MFMA(t+1) consume the SAME bu = {pAu,pBu,h1p(t+1),0} (LSTM3's A upper half
// is zero so the h1p word is inert there). bu is carried across iterations.
// Lane l: n=l&15 (seq col / A-row), g=l>>4 (k-group).
__global__ __launch_bounds__(256, 1)
void lstm3_kernel(const float* __restrict__ x,
                  const float* __restrict__ w_ih1, const float* __restrict__ w_hh1,
                  const float* __restrict__ b_ih1, const float* __restrict__ b_hh1,
                  const float* __restrict__ w_ih2, const float* __restrict__ w_hh2,
                  const float* __restrict__ b_ih2, const float* __restrict__ b_hh2,
                  const float* __restrict__ w_ih3, const float* __restrict__ w_hh3,
                  const float* __restrict__ b_ih3, const float* __restrict__ b_hh3,
                  const float* __restrict__ w_lin, const float* __restrict__ b_lin,
                  float* __restrict__ out, int T)
{
  const int tid = threadIdx.x;
  const int l   = tid & 63;
  const int n   = l & 15;
  const int g   = l >> 4;
  const int wv  = tid >> 6;
  const int seq = 16 * (blockIdx.x * 4 + wv) + n;

  // ---------------- LSTM1 (pre-scaled): rows g (i/f) and 4+g (g-gate/o) ----------------
  const int rA = g, rB = 4 + g;
  const float sAq = L2E_N;
  const float sBq = (g < 2) ? L2E2_N : L2E_N;
  const float m1  = (g < 2) ? 2.0f : 1.0f;
  const float a1  = (g < 2) ? -1.0f : 0.0f;
  const float w1ax = w_ih1[2*rA]*sAq,  w1ay = w_ih1[2*rA+1]*sAq;
  const float w1ah0 = w_hh1[2*rA]*sAq, w1ah1 = w_hh1[2*rA+1]*sAq;
  const float bbA  = (b_ih1[rA] + b_hh1[rA]) * sAq;
  const float w1bx = w_ih1[2*rB]*sBq,  w1by = w_ih1[2*rB+1]*sBq;
  const float w1bh0 = w_hh1[2*rB]*sBq, w1bh1 = w_hh1[2*rB+1]*sBq;
  const float bbB  = (b_ih1[rB] + b_hh1[rB]) * sBq;

  // ---------------- LSTM2: merged A fragments (w_hh2 lower + w_ih2 upper on g0) ----------------
  f16x8 af[4];
  f32x4 cb[4];
  #pragma unroll
  for (int t = 0; t < 4; ++t){
    const float sc = (t == 2) ? L2E2_N : L2E_N;
    #pragma unroll
    for (int e = 0; e < 8; ++e){
      float v = 0.0f;
      if (e < 4)                 v = w_hh2[(16*t + n)*16 + (4*g + e)];
      else if (g == 0 && e < 6)  v = w_ih2[(16*t + n)*2 + (e - 4)];
      af[t][e] = (_Float16)(v * sc);
    }
    #pragma unroll
    for (int j = 0; j < 4; ++j){
      const int r = 16*t + 4*g + j;
      cb[t][j] = (b_ih2[r] + b_hh2[r]) * sc;
    }
  }

  // ---------------- LSTM3 lane-local (pre-scaled): A row n = gate (n&3) ----------------
  const float s3n = ((n & 3) == 2) ? L2E2_N : L2E_N;
  f16x8 a3f;
  #pragma unroll
  for (int e = 0; e < 8; ++e){
    float v = 0.0f;
    if (e < 4) v = w_ih3[16*(n & 3) + 4*g + e] * s3n;
    a3f[e] = (_Float16)v;
  }
  f32x4 c3v;
  c3v[0] = (b_ih3[0] + b_hh3[0]) * L2E_N;
  c3v[1] = (b_ih3[1] + b_hh3[1]) * L2E_N;
  c3v[2] = (b_ih3[2] + b_hh3[2]) * L2E2_N;
  c3v[3] = (b_ih3[3] + b_hh3[3]) * L2E_N;
  const float wh30 = w_hh3[0] * L2E_N,  wh31 = w_hh3[1] * L2E_N;
  const float wh32 = w_hh3[2] * L2E2_N, wh33 = w_hh3[3] * L2E_N;
  const float wl = w_lin[0], bl = b_lin[0];

  // ---------------- state ----------------
  float c1 = 0.f, c3 = 0.f;
  float c2[4] = {0.f, 0.f, 0.f, 0.f};
  float h1a_all = 0.f, h1b_all = 0.f, h3 = 0.f;
  unsigned h1p = 0u;

  const float* xrow = x + (size_t)seq * (size_t)(2*T);
  float*       orow = out + (size_t)seq * (size_t)T;

  float2 x_use = *(const float2*)(xrow);
  float2 x_pre = *(const float2*)(xrow + 2);

  #define LSTM1_STEP(X0, X1)                                                   \
  {                                                                            \
    const float gA = fmaf(w1ax, (X0), fmaf(w1ay, (X1),                         \
                     fmaf(w1ah0, h1a_all, fmaf(w1ah1, h1b_all, bbA))));        \
    const float gB = fmaf(w1bx, (X0), fmaf(w1by, (X1),                         \
                     fmaf(w1bh0, h1a_all, fmaf(w1bh1, h1b_all, bbB))));        \
    const float zA = sgm(gA);                                                  \
    const float zB = fmaf(sgm(gB), m1, a1);                                    \
    const float ig1 = zA * zB;                                                 \
    const float fm = shx(zA, 32);                                              \
    c1 = fmaf(fm, c1, ig1);                                                    \
    const float th1 = tnc(c1);                                                 \
    const float om = shx(zB, 32);                                              \
    const float h1v = om * th1;                                                \
    const float t16 = shx(h1v, 16);                                            \
    h1p = pkrtz(h1v, t16);   /* meaningful on g0 lanes */                      \
    const float a_c = (g & 1) ? t16 : h1v;                                     \
    const float b_c = (g & 1) ? h1v : t16;                                     \
    const float a32 = shx(a_c, 32);                                            \
    const float b32 = shx(b_c, 32);                                            \
    h1a_all = (g & 2) ? a32 : a_c;                                             \
    h1b_all = (g & 2) ? b32 : b_c;                                             \
  }

  LSTM1_STEP(x_use.x, x_use.y)        // h1(0) -> h1p

  // carried B operand for step 0: h2_prev = 0, h1p(0)
  u32x4 bu; bu[0] = 0u; bu[1] = 0u; bu[2] = h1p; bu[3] = 0u;

  float o0 = 0.f, o1 = 0.f, o2 = 0.f, o3 = 0.f;

  const int NCH = T / 4;
  for (int ch = 0; ch < NCH; ++ch){
    const bool cap = (g == (ch & 3));

    #pragma unroll
    for (int s = 0; s < 4; ++s){
      // ---------- main MFMA: gates(t) = W_hh2*h2(t-1) + W_ih2*h1(t) + bias ----------
      const f16x8 bv = __builtin_bit_cast(f16x8, bu);
      const f32x4 d0 = __builtin_amdgcn_mfma_f32_16x16x32_f16(af[0], bv, cb[0], 0, 0, 0);
      const f32x4 d1 = __builtin_amdgcn_mfma_f32_16x16x32_f16(af[1], bv, cb[1], 0, 0, 0);
      const f32x4 d2 = __builtin_amdgcn_mfma_f32_16x16x32_f16(af[2], bv, cb[2], 0, 0, 0);
      const f32x4 d3 = __builtin_amdgcn_mfma_f32_16x16x32_f16(af[3], bv, cb[3], 0, 0, 0);

      // ---------- x advance + prefetch (fills MFMA shadow) ----------
      const float2 xv = x_pre;
      const int ti = 4*ch + s + 2;
      const int tc = (ti < T) ? ti : (T - 1);
      x_pre = *(const float2*)(xrow + 2*tc);

      // ---------- LSTM1 for step t+1 (independent; interleaves with MFMA) ----------
      LSTM1_STEP(xv.x, xv.y)

      // ---------- LSTM2 activations + cell ----------
      float h2l[4];
      #pragma unroll
      for (int j = 0; j < 4; ++j){
        const float ii = sgm(d0[j]);
        const float ff = sgm(d1[j]);
        const float gg = fmaf(2.f, sgm(d2[j]), -1.f);
        const float oo = sgm(d3[j]);
        c2[j] = fmaf(ff, c2[j], ii * gg);
        h2l[j] = oo * tnc(c2[j]);
      }

      // ---------- build shared B for {LSTM3(t), main MFMA(t+1)} ----------
      bu[0] = pkrtz(h2l[0], h2l[1]);
      bu[1] = pkrtz(h2l[2], h2l[3]);
      bu[2] = h1p;                      // h1(t+1); inert in LSTM3 (A upper = 0)
      const f16x8 b3v = __builtin_bit_cast(f16x8, bu);

      // ---------- LSTM3: lane-local (all 4 gates in d3v; no shuffles) ----------
      const f32x4 d3v = __builtin_amdgcn_mfma_f32_16x16x32_f16(a3f, b3v, c3v, 0, 0, 0);
      const float p_i = fmaf(wh30, h3, d3v[0]);
      const float p_f = fmaf(wh31, h3, d3v[1]);
      const float p_g = fmaf(wh32, h3, d3v[2]);
      const float p_o = fmaf(wh33, h3, d3v[3]);
      const float i3 = sgm(p_i);
      const float f3 = sgm(p_f);
      const float g3 = fmaf(2.f, sgm(p_g), -1.f);
      const float q3 = sgm(p_o);
      c3 = fmaf(f3, c3, i3 * g3);
      h3 = q3 * tnc(c3);
      const float yv = fmaf(wl, h3, bl);

      if      (s == 0) o0 = cap ? yv : o0;
      else if (s == 1) o1 = cap ? yv : o1;
      else if (s == 2) o2 = cap ? yv : o2;
      else             o3 = cap ? yv : o3;
    }

    if ((ch & 3) == 3){
      float4 o4; o4.x = o0; o4.y = o1; o4.z = o2; o4.w = o3;
      *(float4*)(orow + (ch >> 2) * 16 + 4 * g) = o4;
    }
  }
  #undef LSTM1_STEP
}

extern "C" void kernel_launch(void* const* d_in, const int* in_sizes, int n_in,
                              void* d_out, int out_size, void* d_ws, size_t ws_size,
                              hipStream_t stream)
{
  const float* x     = (const float*)d_in[0];
  const float* w_ih1 = (const float*)d_in[1];
  const float* w_hh1 = (const float*)d_in[2];
  const float* b_ih1 = (const float*)d_in[3];
  const float* b_hh1 = (const float*)d_in[4];
  const float* w_ih2 = (const float*)d_in[5];
  const float* w_hh2 = (const float*)d_in[6];
  const float* b_ih2 = (const float*)d_in[7];
  const float* b_hh2 = (const float*)d_in[8];
  const float* w_ih3 = (const float*)d_in[9];
  const float* w_hh3 = (const float*)d_in[10];
  const float* b_ih3 = (const float*)d_in[11];
  const float* b_hh3 = (const float*)d_in[12];
  const float* w_lin = (const float*)d_in[13];
  const float* b_lin = (const float*)d_in[14];
  float* out = (float*)d_out;

  const int T = 2048;
  const int B = in_sizes[0] / (2 * T);     // 16384
  const int waves   = B / 16;              // 1024
  const int blocks  = waves / 4;           // 256

  lstm3_kernel<<<blocks, 256, 0, stream>>>(
      x, w_ih1, w_hh1, b_ih1, b_hh1,
      w_ih2, w_hh2, b_ih2, b_hh2,
      w_ih3, w_hh3, b_ih3, b_hh3,
      w_lin, b_lin, out, T);
}